// Round 6
// baseline (164.378 us; speedup 1.0000x reference)
//
#include <hip/hip_runtime.h>
#include <math.h>

#define VOCAB   32000
#define BLTOT   128    // B*L
#define HTOT    64     // H = 8 heads * 8 hph
#define BLT     8      // bl rows accumulated per thread
#define VPB     256    // threads per block (4 waves)
// grid: x = VOCAB/VPB = 125, y = BLTOT/BLT = 16  -> 2000 blocks (R3 config)

#define LOG2E   1.44269504088896340736f

typedef float v2f __attribute__((ext_vector_type(2)));

// packed fp32 (VOP3P, gfx90a+)
static __device__ __forceinline__ v2f pk_mul(v2f a, v2f b) {
    v2f d;
    asm("v_pk_mul_f32 %0, %1, %2" : "=v"(d) : "v"(a), "v"(b));
    return d;
}
static __device__ __forceinline__ v2f pk_fma(v2f a, v2f b, v2f c) {
    asm("v_pk_fma_f32 %0, %1, %2, %0" : "+v"(c) : "v"(a), "v"(b));
    return c;
}

// ---------------------------------------------------------------------------
// Prep: 96 KB table in ws, per (bl, jj): [ef4 | emf4 | cw4]
//   ef  = e^f = 2^(f*log2e),  emf = e^-f,  cw = amps*cos(phases-ip[j])*W[j/8]
//   |f| <= ~5.5 so e^|f| <= ~250: no overflow; products <= ~6e4, finite.
// ---------------------------------------------------------------------------
__global__ void prep_kernel(const float* __restrict__ freqs,
                            const float* __restrict__ amps,
                            const float* __restrict__ phases,
                            const float* __restrict__ ip,
                            const float* __restrict__ W,
                            float* __restrict__ ws) {
    int t = blockIdx.x * blockDim.x + threadIdx.x;   // 0 .. 8191
    if (t >= BLTOT * HTOT) return;
    int bl = t >> 6;
    int j  = t & 63;
    float fe = freqs[t] * LOG2E;
    float cw = amps[t] * cosf(phases[t] - ip[j]) * W[j >> 3];
    int jj = j >> 2, u = j & 3;
    float* base = ws + bl * 192 + jj * 12;
    base[u]     = __builtin_amdgcn_exp2f(fe);    // e^f
    base[4 + u] = __builtin_amdgcn_exp2f(-fe);   // e^-f
    base[8 + u] = cw;
}

// ---------------------------------------------------------------------------
// Main (R3 skeleton, min-trick math): thread owns one vocab row v, BLT=8 bl
// rows in packed accumulators.  exp(-|f-v|) = min(e^f*e^-v, e^-f*e^v).
// Per-thread exps: 8 per jj (was 32 in R3) -> exp count /4.  Inner per
// (jj,i): 3 broadcast ds_read_b128 + 4 pk_mul + 4 v_min + 2 pk_fma.
// ---------------------------------------------------------------------------
__global__ __launch_bounds__(VPB, 4) void
wave_main(const float* __restrict__ vp,     // vocab_patterns, VOCAB x 64
          const float* __restrict__ uni,    // ws table
          const float* __restrict__ bptr,   // bias (1 elem)
          float* __restrict__ out) {        // (B*L, VOCAB)
    const int tid = threadIdx.x;
    const int v   = blockIdx.x * VPB + tid;           // 32000 = 125*256 exact
    const int bl0 = blockIdx.y * BLT;                 // 128 = 16*8 exact

    __shared__ float4 smem[BLT * 16 * 3];             // 6 KB: [ef4|emf4|cw4]

    // stage this block's table slice: 384 float4 = 6 KB
    {
        const float4* src4 = (const float4*)(uni + bl0 * 192);
#pragma unroll
        for (int s = tid; s < BLT * 16 * 3; s += VPB)
            smem[s] = src4[s];
    }
    __syncthreads();

    const float4* __restrict__ vp4 = (const float4*)vp;

    v2f acc01[BLT], acc23[BLT];
#pragma unroll
    for (int i = 0; i < BLT; ++i) { acc01[i] = (v2f)(0.0f); acc23[i] = (v2f)(0.0f); }

#pragma unroll 2
    for (int jj = 0; jj < 16; ++jj) {
        const float4 vf = vp4[v * 16 + jj];           // per-thread vector load
        // v-side exponentials, 8 per jj, amortized over 8 bl rows
        v2f ev01, ev23, emv01, emv23;
        {
            float ax = vf.x * LOG2E, ay = vf.y * LOG2E;
            float az = vf.z * LOG2E, aw = vf.w * LOG2E;
            ev01.x  = __builtin_amdgcn_exp2f( ax);  emv01.x = __builtin_amdgcn_exp2f(-ax);
            ev01.y  = __builtin_amdgcn_exp2f( ay);  emv01.y = __builtin_amdgcn_exp2f(-ay);
            ev23.x  = __builtin_amdgcn_exp2f( az);  emv23.x = __builtin_amdgcn_exp2f(-az);
            ev23.y  = __builtin_amdgcn_exp2f( aw);  emv23.y = __builtin_amdgcn_exp2f(-aw);
        }
#pragma unroll
        for (int i = 0; i < BLT; ++i) {
            const int base = (i * 16 + jj) * 3;
            const float4 ef4  = smem[base];           // e^f,  broadcast
            const float4 emf4 = smem[base + 1];       // e^-f, broadcast
            const float4 cw4  = smem[base + 2];       // cw,   broadcast
            v2f t1 = pk_mul(v2f{ef4.x,  ef4.y},  emv01);
            v2f t2 = pk_mul(v2f{emf4.x, emf4.y}, ev01);
            v2f t3 = pk_mul(v2f{ef4.z,  ef4.w},  emv23);
            v2f t4 = pk_mul(v2f{emf4.z, emf4.w}, ev23);
            v2f m01, m23;
            m01.x = fminf(t1.x, t2.x);  m01.y = fminf(t1.y, t2.y);
            m23.x = fminf(t3.x, t4.x);  m23.y = fminf(t3.y, t4.y);
            acc01[i] = pk_fma(v2f{cw4.x, cw4.y}, m01, acc01[i]);
            acc23[i] = pk_fma(v2f{cw4.z, cw4.w}, m23, acc23[i]);
        }
    }

    const float b0 = bptr[0];
#pragma unroll
    for (int i = 0; i < BLT; ++i) {
        float s = (acc01[i].x + acc01[i].y) + (acc23[i].x + acc23[i].y);
        out[(bl0 + i) * VOCAB + v] = s + b0;          // coalesced stores
    }
}

extern "C" void kernel_launch(void* const* d_in, const int* in_sizes, int n_in,
                              void* d_out, int out_size, void* d_ws, size_t ws_size,
                              hipStream_t stream) {
    const float* freqs  = (const float*)d_in[0];
    const float* amps   = (const float*)d_in[1];
    const float* phases = (const float*)d_in[2];
    const float* vp     = (const float*)d_in[3];
    const float* ip     = (const float*)d_in[4];
    const float* W      = (const float*)d_in[5];
    const float* b      = (const float*)d_in[6];
    float* out = (float*)d_out;
    float* ws  = (float*)d_ws;   // needs 96 KB

    // 1) build uniform {e^f, e^-f, cw} table
    prep_kernel<<<dim3(32), dim3(256), 0, stream>>>(freqs, amps, phases, ip, W, ws);

    // 2) main interference kernel: 125 vocab tiles x 16 bl-groups (2000 blocks)
    wave_main<<<dim3(VOCAB / VPB, BLTOT / BLT), dim3(VPB), 0, stream>>>(vp, ws, b, out);
}

// Round 8
// 120.662 us; speedup vs baseline: 1.3623x; 1.3623x over previous
//
#include <hip/hip_runtime.h>
#include <math.h>

#define VOCAB   32000
#define BLTOT   128    // B*L
#define HTOT    64     // H = 8 heads * 8 hph
#define BLT     8      // bl rows accumulated per thread
#define VPB     256    // threads per block (4 waves)
#define VT      2      // vocab rows per thread
#define GRIDX   ((VOCAB + VPB * VT - 1) / (VPB * VT))   // 63 (tail-guarded)

#define LOG2E   1.44269504088896340736f

typedef __fp16 h2 __attribute__((ext_vector_type(2)));   // matches cvt_pkrtz/fdot2

// ---------------------------------------------------------------------------
// Prep: f16 tables in ws:
//   arrA [bl][jj][8]: {ef0..3, emf0..3}  (16 B per (bl,jj)) at ws+0     (32 KB)
//   arrC [bl][jj][4]: {cw0..3}           ( 8 B per (bl,jj)) at ws+32768 (16 KB)
//   ef = e^f, emf = e^-f, cw = amps*cos(phases-ip[j])*W[j/8]
//   exp(-|f-v|) = min(ef*e^-v, emf*e^v); one-sided f16 overflow is healed
//   by the min (other side is <= 1); both-sided overflow impossible.
// ---------------------------------------------------------------------------
__global__ void prep_kernel(const float* __restrict__ freqs,
                            const float* __restrict__ amps,
                            const float* __restrict__ phases,
                            const float* __restrict__ ip,
                            const float* __restrict__ W,
                            void* __restrict__ ws) {
    int t = blockIdx.x * blockDim.x + threadIdx.x;   // 0 .. 8191
    if (t >= BLTOT * HTOT) return;
    int bl = t >> 6;
    int j  = t & 63;
    float fe = freqs[t] * LOG2E;
    float cw = amps[t] * cosf(phases[t] - ip[j]) * W[j >> 3];
    int jj = j >> 2, u = j & 3;
    __fp16* pA = (__fp16*)ws;
    __fp16* pC = (__fp16*)((char*)ws + 32768);
    int ia = (bl * 16 + jj) * 8;
    pA[ia + u]     = (__fp16)__builtin_amdgcn_exp2f(fe);    // e^f
    pA[ia + 4 + u] = (__fp16)__builtin_amdgcn_exp2f(-fe);   // e^-f
    pC[(bl * 16 + jj) * 4 + u] = (__fp16)cw;
}

// ---------------------------------------------------------------------------
// Main: thread owns VT=2 vocab rows x BLT=8 bl rows.
// Inner per (jj,i): 1 ds_read_b128 ({ef,emf} 8 x f16) + 1 ds_read_b64 (cw)
// serving VT*4 = 8 elements; per (i,k): 4 v_pk_mul_f16 + 2 v_pk_min_f16 +
// 2 v_dot2_f32_f16 (f32 accumulate) -- all full-rate 2-cy packed ops.
// v-side exps: 8 v_exp_f32 + 4 cvt_pkrtz per (jj,k), amortized over BLT=8.
// ---------------------------------------------------------------------------
__global__ __launch_bounds__(VPB, 4) void
wave_main(const float4* __restrict__ vp4,   // vocab_patterns as float4, VOCAB x 16
          const void* __restrict__ uni,     // ws f16 tables
          const float* __restrict__ bptr,   // bias (1 elem)
          float* __restrict__ out) {        // (B*L, VOCAB)
    const int tid = threadIdx.x;
    const int v0  = blockIdx.x * (VPB * VT) + tid;
    const int bl0 = blockIdx.y * BLT;                 // 128 = 16*8 exact

    __shared__ float4 smemA[BLT * 16];   // 2 KB
    __shared__ float2 smemC[BLT * 16];   // 1 KB

    {
        const float4* gA = (const float4*)((const char*)uni + (size_t)bl0 * 256);
        const float2* gC = (const float2*)((const char*)uni + 32768 + (size_t)bl0 * 128);
        if (tid < BLT * 16)            smemA[tid]            = gA[tid];
        else if (tid < 2 * BLT * 16)   smemC[tid - BLT * 16] = gC[tid - BLT * 16];
    }
    __syncthreads();

    int vidx[VT];
#pragma unroll
    for (int k = 0; k < VT; ++k) {
        int v = v0 + k * VPB;
        vidx[k] = v < VOCAB ? v : VOCAB - 1;   // clamp loads; stores guarded
    }

    float acc[BLT][VT];
#pragma unroll
    for (int i = 0; i < BLT; ++i)
#pragma unroll
        for (int k = 0; k < VT; ++k) acc[i][k] = 0.0f;

#pragma unroll 2
    for (int jj = 0; jj < 16; ++jj) {
        h2 evA[VT], evB[VT], emvA[VT], emvB[VT];
#pragma unroll
        for (int k = 0; k < VT; ++k) {
            const float4 vf = vp4[vidx[k] * 16 + jj];
            float ax = vf.x * LOG2E, ay = vf.y * LOG2E;
            float az = vf.z * LOG2E, aw = vf.w * LOG2E;
            evA[k]  = __builtin_amdgcn_cvt_pkrtz(__builtin_amdgcn_exp2f( ax),
                                                 __builtin_amdgcn_exp2f( ay));
            evB[k]  = __builtin_amdgcn_cvt_pkrtz(__builtin_amdgcn_exp2f( az),
                                                 __builtin_amdgcn_exp2f( aw));
            emvA[k] = __builtin_amdgcn_cvt_pkrtz(__builtin_amdgcn_exp2f(-ax),
                                                 __builtin_amdgcn_exp2f(-ay));
            emvB[k] = __builtin_amdgcn_cvt_pkrtz(__builtin_amdgcn_exp2f(-az),
                                                 __builtin_amdgcn_exp2f(-aw));
        }
#pragma unroll
        for (int i = 0; i < BLT; ++i) {
            const float4 A = smemA[i * 16 + jj];      // ds_read_b128, broadcast
            const float2 C = smemC[i * 16 + jj];      // ds_read_b64,  broadcast
            const h2 ef01 = __builtin_bit_cast(h2, A.x);
            const h2 ef23 = __builtin_bit_cast(h2, A.y);
            const h2 em01 = __builtin_bit_cast(h2, A.z);
            const h2 em23 = __builtin_bit_cast(h2, A.w);
            const h2 cw01 = __builtin_bit_cast(h2, C.x);
            const h2 cw23 = __builtin_bit_cast(h2, C.y);
#pragma unroll
            for (int k = 0; k < VT; ++k) {
                h2 m01 = __builtin_elementwise_min(ef01 * emvA[k], em01 * evA[k]);
                h2 m23 = __builtin_elementwise_min(ef23 * emvB[k], em23 * evB[k]);
                acc[i][k] = __builtin_amdgcn_fdot2(m01, cw01, acc[i][k], false);
                acc[i][k] = __builtin_amdgcn_fdot2(m23, cw23, acc[i][k], false);
            }
        }
    }

    const float b0 = bptr[0];
#pragma unroll
    for (int i = 0; i < BLT; ++i)
#pragma unroll
        for (int k = 0; k < VT; ++k) {
            int v = v0 + k * VPB;
            if (v < VOCAB)
                out[(bl0 + i) * VOCAB + v] = acc[i][k] + b0;   // coalesced per k
        }
}

extern "C" void kernel_launch(void* const* d_in, const int* in_sizes, int n_in,
                              void* d_out, int out_size, void* d_ws, size_t ws_size,
                              hipStream_t stream) {
    const float* freqs  = (const float*)d_in[0];
    const float* amps   = (const float*)d_in[1];
    const float* phases = (const float*)d_in[2];
    const float* vp     = (const float*)d_in[3];
    const float* ip     = (const float*)d_in[4];
    const float* W      = (const float*)d_in[5];
    const float* b      = (const float*)d_in[6];
    float* out = (float*)d_out;

    // 1) build f16 {e^f, e^-f | cw} tables (48 KB of ws)
    prep_kernel<<<dim3(32), dim3(256), 0, stream>>>(freqs, amps, phases, ip, W, d_ws);

    // 2) main interference kernel: 63 vocab tiles x 16 bl-groups (1008 blocks)
    wave_main<<<dim3(GRIDX, BLTOT / BLT), dim3(VPB), 0, stream>>>(
        (const float4*)vp, d_ws, b, out);
}

// Round 9
// 115.614 us; speedup vs baseline: 1.4218x; 1.0437x over previous
//
#include <hip/hip_runtime.h>
#include <math.h>

#define VOCAB   32000
#define BLTOT   128    // B*L
#define HTOT    64     // H = 8 heads * 8 hph
#define BLT     4      // bl rows accumulated per thread
#define VPB     256    // threads per block (4 waves)
#define VT      2      // vocab rows per thread
#define NSLICE  ((VOCAB + VPB * VT - 1) / (VPB * VT))   // 63 vocab slices (tail-guarded)

#define LOG2E   1.44269504088896340736f

typedef __fp16 h2 __attribute__((ext_vector_type(2)));   // matches cvt_pkrtz/fdot2

// ---------------------------------------------------------------------------
// Prep: f16 tables in ws:
//   arrA [bl][jj][8]: {ef0..3, emf0..3}  (16 B per (bl,jj)) at ws+0     (32 KB)
//   arrC [bl][jj][4]: {cw0..3}           ( 8 B per (bl,jj)) at ws+32768 (16 KB)
//   ef = e^f, emf = e^-f, cw = amps*cos(phases-ip[j])*W[j/8]
//   exp(-|f-v|) = min(ef*e^-v, emf*e^v); one-sided f16 overflow healed by min.
// ---------------------------------------------------------------------------
__global__ void prep_kernel(const float* __restrict__ freqs,
                            const float* __restrict__ amps,
                            const float* __restrict__ phases,
                            const float* __restrict__ ip,
                            const float* __restrict__ W,
                            void* __restrict__ ws) {
    int t = blockIdx.x * blockDim.x + threadIdx.x;   // 0 .. 8191
    if (t >= BLTOT * HTOT) return;
    int bl = t >> 6;
    int j  = t & 63;
    float fe = freqs[t] * LOG2E;
    float cw = amps[t] * cosf(phases[t] - ip[j]) * W[j >> 3];
    int jj = j >> 2, u = j & 3;
    __fp16* pA = (__fp16*)ws;
    __fp16* pC = (__fp16*)((char*)ws + 32768);
    int ia = (bl * 16 + jj) * 8;
    pA[ia + u]     = (__fp16)__builtin_amdgcn_exp2f(fe);    // e^f
    pA[ia + 4 + u] = (__fp16)__builtin_amdgcn_exp2f(-fe);   // e^-f
    pC[(bl * 16 + jj) * 4 + u] = (__fp16)cw;
}

// ---------------------------------------------------------------------------
// Main: grid (x = 32 bl-groups, y = 63 vocab slices). Consecutive linear
// block ids share one vocab slice -> round-robin across the 8 XCDs, slice
// stays L2-resident (ideal FETCH = 8 XCD x 8 MB = 64 MB).
// Thread owns VT=2 vocab rows x BLT=4 bl rows; 2016 blocks -> ~31 waves/CU.
// Inner per (jj,i): 1 ds_read_b128 + 1 ds_read_b64 serving 8 elements;
// per (i,k): 4 v_pk_mul_f16 + 2 v_pk_min_f16 + 2 v_dot2_f32_f16.
// ---------------------------------------------------------------------------
__global__ __launch_bounds__(VPB, 8) void
wave_main(const float4* __restrict__ vp4,   // vocab_patterns as float4, VOCAB x 16
          const void* __restrict__ uni,     // ws f16 tables
          const float* __restrict__ bptr,   // bias (1 elem)
          float* __restrict__ out) {        // (B*L, VOCAB)
    const int tid = threadIdx.x;
    const int bl0 = blockIdx.x * BLT;                 // 128 = 32*4 exact
    const int v0  = blockIdx.y * (VPB * VT) + tid;

    __shared__ float4 smemA[BLT * 16];   // 1   KB
    __shared__ float2 smemC[BLT * 16];   // 0.5 KB

    {
        const float4* gA = (const float4*)((const char*)uni + (size_t)bl0 * 256);
        const float2* gC = (const float2*)((const char*)uni + 32768 + (size_t)bl0 * 128);
        if (tid < BLT * 16)            smemA[tid]            = gA[tid];
        else if (tid < 2 * BLT * 16)   smemC[tid - BLT * 16] = gC[tid - BLT * 16];
    }
    __syncthreads();

    int vidx[VT];
#pragma unroll
    for (int k = 0; k < VT; ++k) {
        int v = v0 + k * VPB;
        vidx[k] = v < VOCAB ? v : VOCAB - 1;   // clamp loads; stores guarded
    }

    float acc[BLT][VT];
#pragma unroll
    for (int i = 0; i < BLT; ++i)
#pragma unroll
        for (int k = 0; k < VT; ++k) acc[i][k] = 0.0f;

#pragma unroll 2
    for (int jj = 0; jj < 16; ++jj) {
        h2 evA[VT], evB[VT], emvA[VT], emvB[VT];
#pragma unroll
        for (int k = 0; k < VT; ++k) {
            const float4 vf = vp4[vidx[k] * 16 + jj];
            float ax = vf.x * LOG2E, ay = vf.y * LOG2E;
            float az = vf.z * LOG2E, aw = vf.w * LOG2E;
            evA[k]  = __builtin_amdgcn_cvt_pkrtz(__builtin_amdgcn_exp2f( ax),
                                                 __builtin_amdgcn_exp2f( ay));
            evB[k]  = __builtin_amdgcn_cvt_pkrtz(__builtin_amdgcn_exp2f( az),
                                                 __builtin_amdgcn_exp2f( aw));
            emvA[k] = __builtin_amdgcn_cvt_pkrtz(__builtin_amdgcn_exp2f(-ax),
                                                 __builtin_amdgcn_exp2f(-ay));
            emvB[k] = __builtin_amdgcn_cvt_pkrtz(__builtin_amdgcn_exp2f(-az),
                                                 __builtin_amdgcn_exp2f(-aw));
        }
#pragma unroll
        for (int i = 0; i < BLT; ++i) {
            const float4 A = smemA[i * 16 + jj];      // ds_read_b128, broadcast
            const float2 C = smemC[i * 16 + jj];      // ds_read_b64,  broadcast
            const h2 ef01 = __builtin_bit_cast(h2, A.x);
            const h2 ef23 = __builtin_bit_cast(h2, A.y);
            const h2 em01 = __builtin_bit_cast(h2, A.z);
            const h2 em23 = __builtin_bit_cast(h2, A.w);
            const h2 cw01 = __builtin_bit_cast(h2, C.x);
            const h2 cw23 = __builtin_bit_cast(h2, C.y);
#pragma unroll
            for (int k = 0; k < VT; ++k) {
                h2 m01 = __builtin_elementwise_min(ef01 * emvA[k], em01 * evA[k]);
                h2 m23 = __builtin_elementwise_min(ef23 * emvB[k], em23 * evB[k]);
                acc[i][k] = __builtin_amdgcn_fdot2(m01, cw01, acc[i][k], false);
                acc[i][k] = __builtin_amdgcn_fdot2(m23, cw23, acc[i][k], false);
            }
        }
    }

    const float b0 = bptr[0];
#pragma unroll
    for (int i = 0; i < BLT; ++i)
#pragma unroll
        for (int k = 0; k < VT; ++k) {
            int v = v0 + k * VPB;
            if (v < VOCAB)
                out[(bl0 + i) * VOCAB + v] = acc[i][k] + b0;   // coalesced per k
        }
}

extern "C" void kernel_launch(void* const* d_in, const int* in_sizes, int n_in,
                              void* d_out, int out_size, void* d_ws, size_t ws_size,
                              hipStream_t stream) {
    const float* freqs  = (const float*)d_in[0];
    const float* amps   = (const float*)d_in[1];
    const float* phases = (const float*)d_in[2];
    const float* vp     = (const float*)d_in[3];
    const float* ip     = (const float*)d_in[4];
    const float* W      = (const float*)d_in[5];
    const float* b      = (const float*)d_in[6];
    float* out = (float*)d_out;

    // 1) build f16 {e^f, e^-f | cw} tables (48 KB of ws)
    prep_kernel<<<dim3(32), dim3(256), 0, stream>>>(freqs, amps, phases, ip, W, d_ws);

    // 2) main kernel: x = bl-groups (fast, shares vocab slice), y = slices
    wave_main<<<dim3(BLTOT / BLT, NSLICE), dim3(VPB), 0, stream>>>(
        (const float4*)vp, d_ws, b, out);
}

// Round 10
// 115.311 us; speedup vs baseline: 1.4255x; 1.0026x over previous
//
#include <hip/hip_runtime.h>
#include <math.h>

#define VOCAB   32000
#define BLTOT   128    // B*L
#define HTOT    64     // H = 8 heads * 8 hph
#define BLT     4      // bl rows accumulated per thread
#define VPB     256    // threads per block (4 waves)
#define VT      4      // vocab rows per thread
#define SLICE   (VPB * VT)                           // 1024 vocab rows per block
#define NSLICE  ((VOCAB + SLICE - 1) / SLICE)        // 32 (tail-guarded)

#define LOG2E   1.44269504088896340736f

typedef __fp16 h2 __attribute__((ext_vector_type(2)));

// ---------------------------------------------------------------------------
// Prep 1: f16 f-side tables in ws:
//   arrA [bl][jj][8]: {ef0..3, emf0..3} at ws+0      (32 KB)
//   arrC [bl][jj][4]: {cw0..3}          at ws+32768  (16 KB)
//   exp(-|f-v|) = min(ef*e^-v, emf*e^v); one-sided f16 overflow healed by min.
// ---------------------------------------------------------------------------
__global__ void prep_kernel(const float* __restrict__ freqs,
                            const float* __restrict__ amps,
                            const float* __restrict__ phases,
                            const float* __restrict__ ip,
                            const float* __restrict__ W,
                            void* __restrict__ ws) {
    int t = blockIdx.x * blockDim.x + threadIdx.x;   // 0 .. 8191
    if (t >= BLTOT * HTOT) return;
    int bl = t >> 6;
    int j  = t & 63;
    float fe = freqs[t] * LOG2E;
    float cw = amps[t] * cosf(phases[t] - ip[j]) * W[j >> 3];
    int jj = j >> 2, u = j & 3;
    __fp16* pA = (__fp16*)ws;
    __fp16* pC = (__fp16*)((char*)ws + 32768);
    int ia = (bl * 16 + jj) * 8;
    pA[ia + u]     = (__fp16)__builtin_amdgcn_exp2f(fe);    // e^f
    pA[ia + 4 + u] = (__fp16)__builtin_amdgcn_exp2f(-fe);   // e^-f
    pC[(bl * 16 + jj) * 4 + u] = (__fp16)cw;
}

// ---------------------------------------------------------------------------
// Prep 2: v-side exponential table, computed ONCE (was recomputed per
// bl-group = 32x redundant, ~132M exps inside the hot kernel's dependency
// chain).  EV[jj][v] = {e^v0..3, e^-v0..3} f16  (16 B) at ws+49152, 8 MB.
// Layout [jj][v] -> main-kernel loads are lane-consecutive (coalesced).
// ---------------------------------------------------------------------------
__global__ void prep_exp_kernel(const float4* __restrict__ vp4,
                                float4* __restrict__ evt4) {
    int t = blockIdx.x * blockDim.x + threadIdx.x;   // 0 .. 511999
    if (t >= VOCAB * 16) return;
    int jj = t / VOCAB;
    int v  = t - jj * VOCAB;
    const float4 vf = vp4[v * 16 + jj];              // strided read (one-time)
    float ax = vf.x * LOG2E, ay = vf.y * LOG2E;
    float az = vf.z * LOG2E, aw = vf.w * LOG2E;
    h2 ev01  = __builtin_amdgcn_cvt_pkrtz(__builtin_amdgcn_exp2f( ax),
                                          __builtin_amdgcn_exp2f( ay));
    h2 ev23  = __builtin_amdgcn_cvt_pkrtz(__builtin_amdgcn_exp2f( az),
                                          __builtin_amdgcn_exp2f( aw));
    h2 emv01 = __builtin_amdgcn_cvt_pkrtz(__builtin_amdgcn_exp2f(-ax),
                                          __builtin_amdgcn_exp2f(-ay));
    h2 emv23 = __builtin_amdgcn_cvt_pkrtz(__builtin_amdgcn_exp2f(-az),
                                          __builtin_amdgcn_exp2f(-aw));
    float4 o;
    o.x = __builtin_bit_cast(float, ev01);
    o.y = __builtin_bit_cast(float, ev23);
    o.z = __builtin_bit_cast(float, emv01);
    o.w = __builtin_bit_cast(float, emv23);
    evt4[t] = o;                                     // coalesced write
}

// ---------------------------------------------------------------------------
// Main: grid (x = 32 bl-groups, y = 32 vocab slices); consecutive ids share
// a vocab slice (XCD round-robin keeps it L2-resident). Thread owns VT=4
// vocab rows x BLT=4 bl rows. Per jj: 4 coalesced 16B EV loads; per (jj,i):
// 1 ds_read_b128 + 1 ds_read_b64 serving 16 elements; per (i,k): 4 pk_mul
// + 2 pk_min + 2 dot2. NO transcendentals in the hot loop.
// ---------------------------------------------------------------------------
__global__ __launch_bounds__(VPB, 8) void
wave_main(const float4* __restrict__ evt4,  // EV table [16][VOCAB]
          const void* __restrict__ uni,     // ws f16 f-side tables
          const float* __restrict__ bptr,   // bias (1 elem)
          float* __restrict__ out) {        // (B*L, VOCAB)
    const int tid = threadIdx.x;
    const int bl0 = blockIdx.x * BLT;                 // 128 = 32*4 exact
    const int v0  = blockIdx.y * SLICE + tid;

    __shared__ float4 smemA[BLT * 16];   // 1   KB
    __shared__ float2 smemC[BLT * 16];   // 0.5 KB
    {
        const float4* gA = (const float4*)((const char*)uni + (size_t)bl0 * 256);
        const float2* gC = (const float2*)((const char*)uni + 32768 + (size_t)bl0 * 128);
        if (tid < BLT * 16)            smemA[tid]            = gA[tid];
        else if (tid < 2 * BLT * 16)   smemC[tid - BLT * 16] = gC[tid - BLT * 16];
    }
    __syncthreads();

    int vidx[VT];
#pragma unroll
    for (int k = 0; k < VT; ++k) {
        int v = v0 + k * VPB;
        vidx[k] = v < VOCAB ? v : VOCAB - 1;   // clamp loads; stores guarded
    }

    float acc[BLT][VT];
#pragma unroll
    for (int i = 0; i < BLT; ++i)
#pragma unroll
        for (int k = 0; k < VT; ++k) acc[i][k] = 0.0f;

#pragma unroll 2
    for (int jj = 0; jj < 16; ++jj) {
        h2 evA[VT], evB[VT], emvA[VT], emvB[VT];
#pragma unroll
        for (int k = 0; k < VT; ++k) {
            const float4 E = evt4[jj * VOCAB + vidx[k]];   // coalesced 16B
            evA[k]  = __builtin_bit_cast(h2, E.x);
            evB[k]  = __builtin_bit_cast(h2, E.y);
            emvA[k] = __builtin_bit_cast(h2, E.z);
            emvB[k] = __builtin_bit_cast(h2, E.w);
        }
#pragma unroll
        for (int i = 0; i < BLT; ++i) {
            const float4 A = smemA[i * 16 + jj];      // ds_read_b128, broadcast
            const float2 C = smemC[i * 16 + jj];      // ds_read_b64,  broadcast
            const h2 ef01 = __builtin_bit_cast(h2, A.x);
            const h2 ef23 = __builtin_bit_cast(h2, A.y);
            const h2 em01 = __builtin_bit_cast(h2, A.z);
            const h2 em23 = __builtin_bit_cast(h2, A.w);
            const h2 cw01 = __builtin_bit_cast(h2, C.x);
            const h2 cw23 = __builtin_bit_cast(h2, C.y);
#pragma unroll
            for (int k = 0; k < VT; ++k) {
                h2 m01 = __builtin_elementwise_min(ef01 * emvA[k], em01 * evA[k]);
                h2 m23 = __builtin_elementwise_min(ef23 * emvB[k], em23 * evB[k]);
                acc[i][k] = __builtin_amdgcn_fdot2(m01, cw01, acc[i][k], false);
                acc[i][k] = __builtin_amdgcn_fdot2(m23, cw23, acc[i][k], false);
            }
        }
    }

    const float b0 = bptr[0];
#pragma unroll
    for (int i = 0; i < BLT; ++i)
#pragma unroll
        for (int k = 0; k < VT; ++k) {
            int v = v0 + k * VPB;
            if (v < VOCAB)
                out[(bl0 + i) * VOCAB + v] = acc[i][k] + b0;   // coalesced per k
        }
}

extern "C" void kernel_launch(void* const* d_in, const int* in_sizes, int n_in,
                              void* d_out, int out_size, void* d_ws, size_t ws_size,
                              hipStream_t stream) {
    const float* freqs  = (const float*)d_in[0];
    const float* amps   = (const float*)d_in[1];
    const float* phases = (const float*)d_in[2];
    const float* vp     = (const float*)d_in[3];
    const float* ip     = (const float*)d_in[4];
    const float* W      = (const float*)d_in[5];
    const float* b      = (const float*)d_in[6];
    float* out = (float*)d_out;

    // 1) f-side f16 tables (48 KB)
    prep_kernel<<<dim3(32), dim3(256), 0, stream>>>(freqs, amps, phases, ip, W, d_ws);

    // 2) v-side exp table (8 MB at ws+49152)
    float4* evt4 = (float4*)((char*)d_ws + 49152);
    prep_exp_kernel<<<dim3((VOCAB * 16 + 255) / 256), dim3(256), 0, stream>>>(
        (const float4*)vp, evt4);

    // 3) main kernel: x = bl-groups (fast, shares vocab slice), y = slices
    wave_main<<<dim3(BLTOT / BLT, NSLICE), dim3(VPB), 0, stream>>>(
        evt4, d_ws, b, out);
}

// Round 11
// 101.921 us; speedup vs baseline: 1.6128x; 1.1314x over previous
//
#include <hip/hip_runtime.h>
#include <math.h>

#define VOCAB   32000
#define BLTOT   128    // B*L
#define HTOT    64     // H = 8 heads * 8 hph
#define BLT     4      // bl rows accumulated per thread
#define VPB     256    // threads per block (4 waves)
#define VT      4      // vocab rows per thread
#define SLICE   (VPB * VT)                           // 1024 vocab rows per block
#define NSLICE  ((VOCAB + SLICE - 1) / SLICE)        // 32 (tail-guarded)

#define LOG2E   1.44269504088896340736f

typedef __fp16 h2 __attribute__((ext_vector_type(2)));

// ---------------------------------------------------------------------------
// Prep 1: f16 f-side tables in ws (block-uniform in main -> s_load):
//   arrA [bl][jj][8]: {ef0..3, emf0..3} at ws+0      (32 KB)
//   arrC [bl][jj][4]: {cw0..3}          at ws+32768  (16 KB)
//   exp(-|f-v|) = min(ef*e^-v, emf*e^v); one-sided f16 overflow healed by min.
// ---------------------------------------------------------------------------
__global__ void prep_kernel(const float* __restrict__ freqs,
                            const float* __restrict__ amps,
                            const float* __restrict__ phases,
                            const float* __restrict__ ip,
                            const float* __restrict__ W,
                            void* __restrict__ ws) {
    int t = blockIdx.x * blockDim.x + threadIdx.x;   // 0 .. 8191
    if (t >= BLTOT * HTOT) return;
    int bl = t >> 6;
    int j  = t & 63;
    float fe = freqs[t] * LOG2E;
    float cw = amps[t] * cosf(phases[t] - ip[j]) * W[j >> 3];
    int jj = j >> 2, u = j & 3;
    __fp16* pA = (__fp16*)ws;
    __fp16* pC = (__fp16*)((char*)ws + 32768);
    int ia = (bl * 16 + jj) * 8;
    pA[ia + u]     = (__fp16)__builtin_amdgcn_exp2f(fe);    // e^f
    pA[ia + 4 + u] = (__fp16)__builtin_amdgcn_exp2f(-fe);   // e^-f
    pC[(bl * 16 + jj) * 4 + u] = (__fp16)cw;
}

// ---------------------------------------------------------------------------
// Prep 2: v-side exp table EV[jj][v] = {e^v0..3, e^-v0..3} f16 (16 B), 8 MB
// at ws+49152.  Thread t = (v, half): reads its own 128 B contiguous vp
// chunk (all cache lines fully consumed -> L1 absorbs the lane stride),
// writes 8 stores lane-consecutive in v (coalesced).  Was t=(jj,v) with a
// 256 B-stride transpose read (~20 us); this should be ~5 us.
// ---------------------------------------------------------------------------
__global__ void prep_exp_kernel(const float4* __restrict__ vp4,
                                float4* __restrict__ evt4) {
    int t = blockIdx.x * blockDim.x + threadIdx.x;   // 0 .. 63999
    if (t >= VOCAB * 2) return;
    int v    = t >> 1;
    int jj0  = (t & 1) * 8;
#pragma unroll
    for (int l = 0; l < 8; ++l) {
        int jj = jj0 + l;
        const float4 vf = vp4[v * 16 + jj];
        float ax = vf.x * LOG2E, ay = vf.y * LOG2E;
        float az = vf.z * LOG2E, aw = vf.w * LOG2E;
        h2 ev01  = __builtin_amdgcn_cvt_pkrtz(__builtin_amdgcn_exp2f( ax),
                                              __builtin_amdgcn_exp2f( ay));
        h2 ev23  = __builtin_amdgcn_cvt_pkrtz(__builtin_amdgcn_exp2f( az),
                                              __builtin_amdgcn_exp2f( aw));
        h2 emv01 = __builtin_amdgcn_cvt_pkrtz(__builtin_amdgcn_exp2f(-ax),
                                              __builtin_amdgcn_exp2f(-ay));
        h2 emv23 = __builtin_amdgcn_cvt_pkrtz(__builtin_amdgcn_exp2f(-az),
                                              __builtin_amdgcn_exp2f(-aw));
        float4 o;
        o.x = __builtin_bit_cast(float, ev01);
        o.y = __builtin_bit_cast(float, ev23);
        o.z = __builtin_bit_cast(float, emv01);
        o.w = __builtin_bit_cast(float, emv23);
        evt4[jj * VOCAB + v] = o;                    // lane-consecutive in v
    }
}

// ---------------------------------------------------------------------------
// Main: grid (x = 32 bl-groups, y = 32 vocab slices); consecutive ids share
// a vocab slice (XCD round-robin keeps it L2-resident). Thread owns VT=4
// vocab rows x BLT=4 bl rows.  f-side table read through block-uniform
// pointers -> s_load_dwordx4/x2 on the scalar pipe (no LDS, no barrier);
// each VOP3P instr reads at most one SGPR operand (legal).  Per jj: 4
// coalesced 16 B EV loads; per (i,k): 4 pk_mul + 2 pk_min + 2 dot2.
// ---------------------------------------------------------------------------
__global__ __launch_bounds__(VPB, 8) void
wave_main(const float4* __restrict__ evt4,  // EV table [16][VOCAB]
          const void* __restrict__ uni,     // ws f16 f-side tables
          const float* __restrict__ bptr,   // bias (1 elem)
          float* __restrict__ out) {        // (B*L, VOCAB)
    const int tid = threadIdx.x;
    const int bl0 = blockIdx.x * BLT;                 // 128 = 32*4 exact
    const int v0  = blockIdx.y * SLICE + tid;

    // block-uniform f-side pointers (compiler proves uniform -> SMEM)
    const float4* gA = (const float4*)((const char*)uni + (size_t)bl0 * 256);
    const float2* gC = (const float2*)((const char*)uni + 32768 + (size_t)bl0 * 128);

    int vidx[VT];
#pragma unroll
    for (int k = 0; k < VT; ++k) {
        int v = v0 + k * VPB;
        vidx[k] = v < VOCAB ? v : VOCAB - 1;   // clamp loads; stores guarded
    }

    float acc[BLT][VT];
#pragma unroll
    for (int i = 0; i < BLT; ++i)
#pragma unroll
        for (int k = 0; k < VT; ++k) acc[i][k] = 0.0f;

#pragma unroll 2
    for (int jj = 0; jj < 16; ++jj) {
        h2 evA[VT], evB[VT], emvA[VT], emvB[VT];
#pragma unroll
        for (int k = 0; k < VT; ++k) {
            const float4 E = evt4[jj * VOCAB + vidx[k]];   // coalesced 16B
            evA[k]  = __builtin_bit_cast(h2, E.x);
            evB[k]  = __builtin_bit_cast(h2, E.y);
            emvA[k] = __builtin_bit_cast(h2, E.z);
            emvB[k] = __builtin_bit_cast(h2, E.w);
        }
#pragma unroll
        for (int i = 0; i < BLT; ++i) {
            const float4 A = gA[i * 16 + jj];         // s_load_dwordx4
            const float2 C = gC[i * 16 + jj];         // s_load_dwordx2
            const h2 ef01 = __builtin_bit_cast(h2, A.x);
            const h2 ef23 = __builtin_bit_cast(h2, A.y);
            const h2 em01 = __builtin_bit_cast(h2, A.z);
            const h2 em23 = __builtin_bit_cast(h2, A.w);
            const h2 cw01 = __builtin_bit_cast(h2, C.x);
            const h2 cw23 = __builtin_bit_cast(h2, C.y);
#pragma unroll
            for (int k = 0; k < VT; ++k) {
                h2 m01 = __builtin_elementwise_min(ef01 * emvA[k], em01 * evA[k]);
                h2 m23 = __builtin_elementwise_min(ef23 * emvB[k], em23 * evB[k]);
                acc[i][k] = __builtin_amdgcn_fdot2(m01, cw01, acc[i][k], false);
                acc[i][k] = __builtin_amdgcn_fdot2(m23, cw23, acc[i][k], false);
            }
        }
    }

    const float b0 = bptr[0];
#pragma unroll
    for (int i = 0; i < BLT; ++i)
#pragma unroll
        for (int k = 0; k < VT; ++k) {
            int v = v0 + k * VPB;
            if (v < VOCAB)
                out[(bl0 + i) * VOCAB + v] = acc[i][k] + b0;   // coalesced per k
        }
}

extern "C" void kernel_launch(void* const* d_in, const int* in_sizes, int n_in,
                              void* d_out, int out_size, void* d_ws, size_t ws_size,
                              hipStream_t stream) {
    const float* freqs  = (const float*)d_in[0];
    const float* amps   = (const float*)d_in[1];
    const float* phases = (const float*)d_in[2];
    const float* vp     = (const float*)d_in[3];
    const float* ip     = (const float*)d_in[4];
    const float* W      = (const float*)d_in[5];
    const float* b      = (const float*)d_in[6];
    float* out = (float*)d_out;

    // 1) f-side f16 tables (48 KB)
    prep_kernel<<<dim3(32), dim3(256), 0, stream>>>(freqs, amps, phases, ip, W, d_ws);

    // 2) v-side exp table (8 MB at ws+49152), coalesced-write version
    float4* evt4 = (float4*)((char*)d_ws + 49152);
    prep_exp_kernel<<<dim3((VOCAB * 2 + 255) / 256), dim3(256), 0, stream>>>(
        (const float4*)vp, evt4);

    // 3) main kernel: x = bl-groups (fast, shares vocab slice), y = slices
    wave_main<<<dim3(BLTOT / BLT, NSLICE), dim3(VPB), 0, stream>>>(
        evt4, d_ws, b, out);
}

// Round 12
// 98.373 us; speedup vs baseline: 1.6710x; 1.0361x over previous
//
#include <hip/hip_runtime.h>
#include <math.h>

#define VOCAB   32000
#define BLTOT   128    // B*L
#define HTOT    64     // H = 8 heads * 8 hph
#define BLT     4      // bl rows accumulated per thread
#define VPB     256    // threads per block (4 waves)
#define VT      4      // vocab rows per thread
#define SLICE   (VPB * VT)                           // 1024 vocab rows per block
#define NSLICE  ((VOCAB + SLICE - 1) / SLICE)        // 32 (tail-guarded)

#define PREP1_BLOCKS 32                              // 8192 threads for f-side
#define PREP2_BLOCKS ((VOCAB * 2 + 255) / 256)       // 250 blocks for EV table

#define LOG2E   1.44269504088896340736f

typedef __fp16 h2 __attribute__((ext_vector_type(2)));

// ---------------------------------------------------------------------------
// Fused prep (single launch, block-range partitioned):
//  blocks [0, 32):    f-side f16 tables in ws (block-uniform in main -> s_load)
//    arrA [bl][jj][8]: {ef0..3, emf0..3} at ws+0      (32 KB)
//    arrC [bl][jj][4]: {cw0..3}          at ws+32768  (16 KB)
//  blocks [32, 282):  v-side exp table EV[jj][v] = {e^v0..3, e^-v0..3} f16,
//    8 MB at ws+49152. Thread = (v, half): reads its own 128 B contiguous
//    vp chunk, writes lane-consecutive in v (coalesced).
//  exp(-|f-v|) = min(ef*e^-v, emf*e^v); one-sided f16 overflow healed by min.
// ---------------------------------------------------------------------------
__global__ void prep_fused(const float* __restrict__ freqs,
                           const float* __restrict__ amps,
                           const float* __restrict__ phases,
                           const float* __restrict__ ip,
                           const float* __restrict__ W,
                           const float4* __restrict__ vp4,
                           void* __restrict__ ws) {
    if (blockIdx.x < PREP1_BLOCKS) {
        int t = blockIdx.x * blockDim.x + threadIdx.x;   // 0 .. 8191
        int bl = t >> 6;
        int j  = t & 63;
        float fe = freqs[t] * LOG2E;
        float cw = amps[t] * cosf(phases[t] - ip[j]) * W[j >> 3];
        int jj = j >> 2, u = j & 3;
        __fp16* pA = (__fp16*)ws;
        __fp16* pC = (__fp16*)((char*)ws + 32768);
        int ia = (bl * 16 + jj) * 8;
        pA[ia + u]     = (__fp16)__builtin_amdgcn_exp2f(fe);    // e^f
        pA[ia + 4 + u] = (__fp16)__builtin_amdgcn_exp2f(-fe);   // e^-f
        pC[(bl * 16 + jj) * 4 + u] = (__fp16)cw;
    } else {
        int t = (blockIdx.x - PREP1_BLOCKS) * blockDim.x + threadIdx.x;  // 0 .. 63999
        if (t >= VOCAB * 2) return;
        int v   = t >> 1;
        int jj0 = (t & 1) * 8;
        float4* evt4 = (float4*)((char*)ws + 49152);
#pragma unroll
        for (int l = 0; l < 8; ++l) {
            int jj = jj0 + l;
            const float4 vf = vp4[v * 16 + jj];
            float ax = vf.x * LOG2E, ay = vf.y * LOG2E;
            float az = vf.z * LOG2E, aw = vf.w * LOG2E;
            h2 ev01  = __builtin_amdgcn_cvt_pkrtz(__builtin_amdgcn_exp2f( ax),
                                                  __builtin_amdgcn_exp2f( ay));
            h2 ev23  = __builtin_amdgcn_cvt_pkrtz(__builtin_amdgcn_exp2f( az),
                                                  __builtin_amdgcn_exp2f( aw));
            h2 emv01 = __builtin_amdgcn_cvt_pkrtz(__builtin_amdgcn_exp2f(-ax),
                                                  __builtin_amdgcn_exp2f(-ay));
            h2 emv23 = __builtin_amdgcn_cvt_pkrtz(__builtin_amdgcn_exp2f(-az),
                                                  __builtin_amdgcn_exp2f(-aw));
            float4 o;
            o.x = __builtin_bit_cast(float, ev01);
            o.y = __builtin_bit_cast(float, ev23);
            o.z = __builtin_bit_cast(float, emv01);
            o.w = __builtin_bit_cast(float, emv23);
            evt4[jj * VOCAB + v] = o;                    // lane-consecutive in v
        }
    }
}

// ---------------------------------------------------------------------------
// Main (unchanged from R11 -- passed, absmax 0.03125): grid (x = 32
// bl-groups, y = 32 vocab slices); consecutive ids share a vocab slice
// (XCD round-robin keeps it L2-resident). Thread owns VT=4 vocab rows x
// BLT=4 bl rows. f-side table via block-uniform pointers -> s_load on the
// scalar pipe (no LDS, no barrier). Per jj: 4 coalesced 16 B EV loads;
// per (i,k): 4 pk_mul + 2 pk_min + 2 dot2. No transcendentals in hot loop.
// ---------------------------------------------------------------------------
__global__ __launch_bounds__(VPB, 8) void
wave_main(const float4* __restrict__ evt4,  // EV table [16][VOCAB]
          const void* __restrict__ uni,     // ws f16 f-side tables
          const float* __restrict__ bptr,   // bias (1 elem)
          float* __restrict__ out) {        // (B*L, VOCAB)
    const int tid = threadIdx.x;
    const int bl0 = blockIdx.x * BLT;                 // 128 = 32*4 exact
    const int v0  = blockIdx.y * SLICE + tid;

    const float4* gA = (const float4*)((const char*)uni + (size_t)bl0 * 256);
    const float2* gC = (const float2*)((const char*)uni + 32768 + (size_t)bl0 * 128);

    int vidx[VT];
#pragma unroll
    for (int k = 0; k < VT; ++k) {
        int v = v0 + k * VPB;
        vidx[k] = v < VOCAB ? v : VOCAB - 1;   // clamp loads; stores guarded
    }

    float acc[BLT][VT];
#pragma unroll
    for (int i = 0; i < BLT; ++i)
#pragma unroll
        for (int k = 0; k < VT; ++k) acc[i][k] = 0.0f;

#pragma unroll 2
    for (int jj = 0; jj < 16; ++jj) {
        h2 evA[VT], evB[VT], emvA[VT], emvB[VT];
#pragma unroll
        for (int k = 0; k < VT; ++k) {
            const float4 E = evt4[jj * VOCAB + vidx[k]];   // coalesced 16B
            evA[k]  = __builtin_bit_cast(h2, E.x);
            evB[k]  = __builtin_bit_cast(h2, E.y);
            emvA[k] = __builtin_bit_cast(h2, E.z);
            emvB[k] = __builtin_bit_cast(h2, E.w);
        }
#pragma unroll
        for (int i = 0; i < BLT; ++i) {
            const float4 A = gA[i * 16 + jj];         // s_load_dwordx4
            const float2 C = gC[i * 16 + jj];         // s_load_dwordx2
            const h2 ef01 = __builtin_bit_cast(h2, A.x);
            const h2 ef23 = __builtin_bit_cast(h2, A.y);
            const h2 em01 = __builtin_bit_cast(h2, A.z);
            const h2 em23 = __builtin_bit_cast(h2, A.w);
            const h2 cw01 = __builtin_bit_cast(h2, C.x);
            const h2 cw23 = __builtin_bit_cast(h2, C.y);
#pragma unroll
            for (int k = 0; k < VT; ++k) {
                h2 m01 = __builtin_elementwise_min(ef01 * emvA[k], em01 * evA[k]);
                h2 m23 = __builtin_elementwise_min(ef23 * emvB[k], em23 * evB[k]);
                acc[i][k] = __builtin_amdgcn_fdot2(m01, cw01, acc[i][k], false);
                acc[i][k] = __builtin_amdgcn_fdot2(m23, cw23, acc[i][k], false);
            }
        }
    }

    const float b0 = bptr[0];
#pragma unroll
    for (int i = 0; i < BLT; ++i)
#pragma unroll
        for (int k = 0; k < VT; ++k) {
            int v = v0 + k * VPB;
            if (v < VOCAB)
                out[(bl0 + i) * VOCAB + v] = acc[i][k] + b0;   // coalesced per k
        }
}

extern "C" void kernel_launch(void* const* d_in, const int* in_sizes, int n_in,
                              void* d_out, int out_size, void* d_ws, size_t ws_size,
                              hipStream_t stream) {
    const float* freqs  = (const float*)d_in[0];
    const float* amps   = (const float*)d_in[1];
    const float* phases = (const float*)d_in[2];
    const float* vp     = (const float*)d_in[3];
    const float* ip     = (const float*)d_in[4];
    const float* W      = (const float*)d_in[5];
    const float* b      = (const float*)d_in[6];
    float* out = (float*)d_out;

    // 1) fused prep: f-side tables (48 KB) + v-side EV table (8 MB) in one launch
    prep_fused<<<dim3(PREP1_BLOCKS + PREP2_BLOCKS), dim3(256), 0, stream>>>(
        freqs, amps, phases, ip, W, (const float4*)vp, d_ws);

    // 2) main kernel: x = bl-groups (fast, shares vocab slice), y = slices
    float4* evt4 = (float4*)((char*)d_ws + 49152);
    wave_main<<<dim3(BLTOT / BLT, NSLICE), dim3(VPB), 0, stream>>>(
        evt4, d_ws, b, out);
}